// Round 1
// 366.040 us; speedup vs baseline: 1.0248x; 1.0248x over previous
//
#include <hip/hip_runtime.h>
#include <hip/hip_bf16.h>
#include <stdint.h>

// Problem constants
#define BB   32
#define CIN  256
#define COUT 256
#define HH   56
#define WW   56
#define HW   3136           // 56*56
#define KEXP 4
#define HP   58             // padded spatial (1-px zero halo)

typedef __attribute__((ext_vector_type(8))) short  short8;
typedef __attribute__((ext_vector_type(4))) float  floatx4;

__device__ __forceinline__ unsigned short f2bf(float f) {
    uint32_t u = __float_as_uint(f);
    u = (u + 0x7fffu + ((u >> 16) & 1u)) >> 16;
    return (unsigned short)u;
}
__device__ __forceinline__ float bf2f(unsigned short s) {
    return __uint_as_float(((uint32_t)s) << 16);
}
__device__ __forceinline__ uint32_t pack2(float a, float b) {
    return (uint32_t)f2bf(a) | ((uint32_t)f2bf(b) << 16);
}

__device__ __forceinline__ void async_copy16(const void* gsrc, void* ldst) {
    __builtin_amdgcn_global_load_lds(
        (const __attribute__((address_space(1))) unsigned int*)gsrc,
        (__attribute__((address_space(3))) unsigned int*)ldst, 16, 0, 0);
}

// ---------------------------------------------------------------------------
// Kernel T: NCHW fp32 -> padded NHWC bf16, plus per-(b,h) pool partials.
// grid: B*H blocks, 256 threads. No atomics: partial[b][h][c] written once.
// Halo: each block zeros w'=0/57 of its row; h==0 blocks zero rows 0 and 57.
// ---------------------------------------------------------------------------
__global__ __launch_bounds__(256) void transpose_pool_kernel(
    const float* __restrict__ x,          // [B][CIN][H][W]
    unsigned short* __restrict__ xt,      // [B][58][58][CIN] bf16, halo zero
    float* __restrict__ partial)          // [B][H][CIN] row sums
{
    __shared__ unsigned short tile[CIN * 62];   // [c][w] stride 62: bank-safe
    const int bx  = blockIdx.x;
    const int b   = bx / HH;
    const int h   = bx % HH;
    const int tid = threadIdx.x;

    const float* xb = x + (size_t)b * CIN * HW + h * WW;

    for (int i = tid; i < CIN * 14; i += 256) {
        const int c  = i / 14;
        const int wv = i % 14;
        const float4 v = *(const float4*)(xb + (size_t)c * HW + wv * 4);
        uint32_t* p = (uint32_t*)&tile[c * 62 + wv * 4];
        p[0] = pack2(v.x, v.y);
        p[1] = pack2(v.z, v.w);
    }
    __syncthreads();

    // per-channel row sum (c = tid)
    {
        float s = 0.f;
        #pragma unroll 8
        for (int i = 0; i < WW; ++i) s += bf2f(tile[tid * 62 + i]);
        partial[((size_t)b * HH + h) * CIN + tid] = s;
    }

    // padded NHWC write, 2 channels per lane (4 B stores)
    unsigned short* row = xt + (((size_t)b * HP + (h + 1)) * HP) * CIN;
    for (int j = tid; j < WW * 128; j += 256) {
        const int w  = j >> 7;
        const int c2 = (j & 127) * 2;
        const uint32_t v = (uint32_t)tile[c2 * 62 + w]
                         | ((uint32_t)tile[(c2 + 1) * 62 + w] << 16);
        *(uint32_t*)&row[(w + 1) * CIN + c2] = v;
    }

    // halo: w'=0 and w'=57 of this row
    if (tid < 128) {
        ((uint32_t*)&row[0])[tid]          = 0u;
        ((uint32_t*)&row[57 * CIN])[tid]   = 0u;
    }
    // halo: full rows h'=0 and h'=57 (only h==0 blocks)
    if (h == 0) {
        uint32_t* r0  = (uint32_t*)(xt + ((size_t)b * HP + 0)  * HP * CIN);
        uint32_t* r57 = (uint32_t*)(xt + ((size_t)b * HP + 57) * HP * CIN);
        for (int i = tid; i < HP * 128; i += 256) { r0[i] = 0u; r57[i] = 0u; }
    }
}

// ---------------------------------------------------------------------------
// Kernel A: pool-partial reduce + attention MLP + softmax -> att[B][K]
// grid: B blocks x 256 threads
// ---------------------------------------------------------------------------
__global__ __launch_bounds__(256) void attn_kernel(
    const float* __restrict__ partial,  // [B][H][CIN]
    const float* __restrict__ fc1w,     // [K][CIN]
    const float* __restrict__ fc1b,     // [K]
    const float* __restrict__ fc2w,     // [K][K]
    const float* __restrict__ fc2b,     // [K]
    float* __restrict__ att)            // [B][K]
{
    __shared__ float pl[CIN];
    const int b   = blockIdx.x;
    const int tid = threadIdx.x;

    float s = 0.f;
    const float* pp = partial + (size_t)b * HH * CIN + tid;
    #pragma unroll 8
    for (int h = 0; h < HH; ++h) s += pp[h * CIN];
    pl[tid] = s * (1.0f / (float)HW);
    __syncthreads();

    if (tid < 64) {
        const int lane = tid;
        float sk[KEXP] = {0.f, 0.f, 0.f, 0.f};
        #pragma unroll
        for (int c0 = 0; c0 < CIN; c0 += 64) {
            const float p = pl[c0 + lane];
            #pragma unroll
            for (int k = 0; k < KEXP; ++k) sk[k] += p * fc1w[k * CIN + c0 + lane];
        }
        #pragma unroll
        for (int off = 32; off > 0; off >>= 1) {
            #pragma unroll
            for (int k = 0; k < KEXP; ++k) sk[k] += __shfl_down(sk[k], off);
        }
        if (lane == 0) {
            float a[KEXP];
            #pragma unroll
            for (int k = 0; k < KEXP; ++k) a[k] = fmaxf(sk[k] + fc1b[k], 0.f);
            float z[KEXP], m = -1e30f;
            #pragma unroll
            for (int j = 0; j < KEXP; ++j) {
                float t = fc2b[j];
                #pragma unroll
                for (int k = 0; k < KEXP; ++k) t += a[k] * fc2w[j * KEXP + k];
                z[j] = t;
                m = fmaxf(m, t);
            }
            float den = 0.f;
            #pragma unroll
            for (int j = 0; j < KEXP; ++j) { z[j] = expf(z[j] - m); den += z[j]; }
            const float inv = 1.0f / den;
            #pragma unroll
            for (int j = 0; j < KEXP; ++j) att[b * KEXP + j] = z[j] * inv;
        }
    }
}

// ---------------------------------------------------------------------------
// Kernel W: aggregate expert weights -> agg_w[b][rs][o][c] (bf16), agg_b[b][o]
// grid: COUT*4 blocks: o = bx>>2, b-quarter = bx&3 (8 samples each).
// ---------------------------------------------------------------------------
__global__ __launch_bounds__(256) void aggw_kernel(
    const float* __restrict__ weight,   // [K][COUT][CIN][3][3]
    const float* __restrict__ bias,     // [K][COUT]
    const float* __restrict__ att,      // [B][K]
    unsigned short* __restrict__ aggw,  // [B][9][COUT][CIN] bf16
    float* __restrict__ aggb)           // [B][COUT]
{
    __shared__ float accw[CIN * 9];     // staging for (c,rs)->(rs,c) transpose
    const int bx  = blockIdx.x;
    const int o   = bx >> 2;
    const int b0  = (bx & 3) * 8;
    const int tid = threadIdx.x;

    float wreg[KEXP][9];
    #pragma unroll
    for (int k = 0; k < KEXP; ++k) {
        const float* wk = weight + (size_t)(k * COUT + o) * (CIN * 9);
        #pragma unroll
        for (int j = 0; j < 9; ++j) wreg[k][j] = wk[j * 256 + tid];
    }
    float bvals[KEXP];
    #pragma unroll
    for (int k = 0; k < KEXP; ++k) bvals[k] = bias[k * COUT + o];

    for (int bi = 0; bi < 8; ++bi) {
        const int b = b0 + bi;
        float av[KEXP];
        #pragma unroll
        for (int k = 0; k < KEXP; ++k) av[k] = att[b * KEXP + k];

        __syncthreads();   // previous iteration's accw reads complete
        #pragma unroll
        for (int j = 0; j < 9; ++j) {
            float r = 0.f;
            #pragma unroll
            for (int k = 0; k < KEXP; ++k) r += av[k] * wreg[k][j];
            accw[j * 256 + tid] = r;   // accw[flat] mirrors weight-flat layout
        }
        __syncthreads();

        // element (c, rs) = accw[c*9 + rs]; write [rs][c] packed pairs
        for (int i = tid; i < 9 * 128; i += 256) {
            const int j  = i >> 7;          // rs
            const int cp = (i & 127) * 2;   // channel pair
            const uint32_t v = pack2(accw[cp * 9 + j], accw[(cp + 1) * 9 + j]);
            *(uint32_t*)&aggw[(((size_t)b * 9 + j) * COUT + o) * CIN + cp] = v;
        }
        if (tid == 0) {
            float sb = 0.f;
            #pragma unroll
            for (int k = 0; k < KEXP; ++k) sb += av[k] * bvals[k];
            aggb[b * COUT + o] = sb;
        }
    }
}

// ---------------------------------------------------------------------------
// Kernel G: per-sample implicit-im2col GEMM, 256x256 tile, 8-phase pipelined
// schedule (T3+T4 counted-vmcnt, T5 setprio, T2-style chunk swizzle).
//
// Geometry: BM=256 (COUT), BN=256 (pixels, 13 tiles/sample), BK=64.
// 512 threads = 8 waves (2M x 4N), per-wave 128x64 output, acc[8][4] f32x4.
// LDS 128 KiB: buf[2] x { A[ks][256r][64B], B[ks][256r][64B] } (k-slice major).
// Swizzle: 16B chunk u within a 64B row -> u ^ ((r>>1)&3); applied on the
// pre-swizzled GLOBAL source (linear LDS dest, m104-safe), inverted on reads.
// Read-side swizzle folds to a lane constant (rows are 16-aligned).
//
// Per K-tile t: 4 phases (mh0,ks0)(mh1,ks0)(mh1,ks1)(mh0,ks1), each:
//   {4-8 ds_read_b128 | stage one half-tile} -> barrier -> setprio(1) ->
//   16 MFMA -> setprio(0) -> [ph4: s_waitcnt vmcnt(4)] -> barrier.
// Stage schedule: ph1->A(t+1)ks1, ph2->B(t+1)ks1, ph3->A(t+2)ks0,
// ph4->B(t+2)ks0.  Invariant at each ph4 vmcnt(4): everything except the
// two just-issued ks0 halves has landed => tile t+1 complete. Every staged
// half overwrites a region last ds_read >=1 barrier earlier (verified per
// region: Aks0 read ph1/ph2, Aks1 ph3/ph4, Bks0 ph1, Bks1 ph3).
// ---------------------------------------------------------------------------
#define PHASE(MH, KS, LOADB, STAGE_STMT, VM_STMT) do {                         \
    const char* Ap_ = lds + bufoff + (KS) * 16384 + lnoff;                     \
    const char* Bp_ = lds + bufoff + 32768 + (KS) * 16384 + lnoff;             \
    short8 af_[4];                                                             \
    if (LOADB) {                                                               \
        _Pragma("unroll")                                                      \
        for (int ni_ = 0; ni_ < 4; ++ni_)                                      \
            bf[ni_] = *(const short8*)(Bp_ + wn * 4096 + ni_ * 1024);          \
    }                                                                          \
    _Pragma("unroll")                                                          \
    for (int mi_ = 0; mi_ < 4; ++mi_)                                          \
        af_[mi_] = *(const short8*)(Ap_ + wm * 8192 + (MH) * 4096 + mi_ * 1024); \
    STAGE_STMT;                                                                \
    asm volatile("" ::: "memory");                                             \
    __builtin_amdgcn_s_barrier();                                              \
    asm volatile("" ::: "memory");                                             \
    __builtin_amdgcn_s_setprio(1);                                             \
    _Pragma("unroll")                                                          \
    for (int mi_ = 0; mi_ < 4; ++mi_)                                          \
        _Pragma("unroll")                                                      \
        for (int ni_ = 0; ni_ < 4; ++ni_)                                      \
            acc[(MH) * 4 + mi_][ni_] = __builtin_amdgcn_mfma_f32_16x16x32_bf16( \
                af_[mi_], bf[ni_], acc[(MH) * 4 + mi_][ni_], 0, 0, 0);         \
    __builtin_amdgcn_s_setprio(0);                                             \
    VM_STMT;                                                                   \
    asm volatile("" ::: "memory");                                             \
    __builtin_amdgcn_s_barrier();                                              \
    asm volatile("" ::: "memory");                                             \
} while (0)

__global__ __launch_bounds__(512, 2) void conv_gemm_kernel(
    const unsigned short* __restrict__ xt,    // [B][58][58][CIN] bf16 padded
    const unsigned short* __restrict__ aggw,  // [B][9][COUT][CIN] bf16
    const float* __restrict__ aggb,           // [B][COUT]
    float* __restrict__ out)                  // [B][COUT][HW]
{
    __shared__ __attribute__((aligned(128))) char lds[131072];

    // grid 416 = 32 b x 13 n-tiles; bijective XCD chunking (416 % 8 == 0):
    // XCD x owns wg in [x*52, (x+1)*52) = exactly 4 consecutive samples.
    const int bx = blockIdx.x;
    const int wg = (bx & 7) * 52 + (bx >> 3);
    const int b  = wg / 13;
    const int p0 = (wg - b * 13) * 256;

    const int tid  = threadIdx.x;
    const int wave = tid >> 6;
    const int lane = tid & 63;
    const int wm   = wave >> 2;                 // 0..1 (M half)
    const int wn   = wave & 3;                  // 0..3 (N quarter)
    const int m    = lane & 15;
    const int q    = lane >> 4;                 // 0..3 k-chunk of fragment
    const int lnoff = m * 64 + ((q ^ (m >> 1)) & 3) * 16;  // read swizzle

    const char* aggw_b = (const char*)aggw + (size_t)b * (9 * COUT * CIN * 2);
    const char* xt_b   = (const char*)xt   + (size_t)b * (HP * HP * CIN * 2);

    // staging geometry: unit n = j*512 + tid; row r = n>>2; chunk u = n&3
    int aoff0, aoff1, boff0, boff1;
    {
        int n = tid, r = n >> 2, u = n & 3, sw = (u ^ (r >> 1)) & 3;
        aoff0 = r * 512 + sw * 16;
        int p = p0 + r; int pv = (p < HW) ? p : 0;
        int h = pv / WW, w = pv - h * WW;
        boff0 = ((h + 1) * HP + (w + 1)) * 512 + sw * 16;

        n = 512 + tid; r = n >> 2; u = n & 3; sw = (u ^ (r >> 1)) & 3;
        aoff1 = r * 512 + sw * 16;
        p = p0 + r; pv = (p < HW) ? p : 0;
        h = pv / WW; w = pv - h * WW;
        boff1 = ((h + 1) * HP + (w + 1)) * 512 + sw * 16;
    }

    auto stageA = [&](int kt, int ks) {
        const int ga = (kt >> 2) * (COUT * CIN * 2) + (kt & 3) * 128 + ks * 64;
        char* d = lds + (kt & 1) * 65536 + ks * 16384 + wave * 1024;
        async_copy16(aggw_b + (ga + aoff0), d);
        async_copy16(aggw_b + (ga + aoff1), d + 8192);
    };
    auto stageB = [&](int kt, int ks) {
        const int rs = kt >> 2;
        const int gb = ((rs / 3 - 1) * HP + (rs % 3 - 1)) * 512
                     + (kt & 3) * 128 + ks * 64;
        char* d = lds + (kt & 1) * 65536 + 32768 + ks * 16384 + wave * 1024;
        async_copy16(xt_b + (gb + boff0), d);
        async_copy16(xt_b + (gb + boff1), d + 8192);
    };

    floatx4 acc[8][4];
    #pragma unroll
    for (int a_ = 0; a_ < 8; ++a_)
        #pragma unroll
        for (int n_ = 0; n_ < 4; ++n_)
            #pragma unroll
            for (int e_ = 0; e_ < 4; ++e_) acc[a_][n_][e_] = 0.f;

    // Prologue: tile 0 complete + tile 1 ks0 in flight (= ph3/ph4 of t=-1).
    stageA(0, 0); stageB(0, 0);
    stageA(0, 1); stageB(0, 1);
    stageA(1, 0); stageB(1, 0);
    asm volatile("s_waitcnt vmcnt(4)" ::: "memory");
    __builtin_amdgcn_s_barrier();
    asm volatile("" ::: "memory");

    // 36 K-tiles (9 taps x 4 channel-blocks), 2 tiles per iteration.
    #pragma unroll 1
    for (int i = 0; i < 18; ++i) {
        const int t0 = 2 * i;
        {
            const int bufoff = 0;
            short8 bf[4];
            PHASE(0, 0, 1, stageA(t0 + 1, 1), ((void)0));
            PHASE(1, 0, 0, stageB(t0 + 1, 1), ((void)0));
            PHASE(1, 1, 1, if (i < 17) stageA(t0 + 2, 0), ((void)0));
            PHASE(0, 1, 0, if (i < 17) stageB(t0 + 2, 0),
                  if (i < 17) { asm volatile("s_waitcnt vmcnt(4)" ::: "memory"); }
                  else        { asm volatile("s_waitcnt vmcnt(0)" ::: "memory"); });
        }
        {
            const int bufoff = 65536;
            const int t1 = 2 * i + 1;
            short8 bf[4];
            PHASE(0, 0, 1, if (i < 17) stageA(t1 + 1, 1), ((void)0));
            PHASE(1, 0, 0, if (i < 17) stageB(t1 + 1, 1), ((void)0));
            PHASE(1, 1, 1, if (i < 17) stageA(t1 + 2, 0), ((void)0));
            PHASE(0, 1, 0, if (i < 17) stageB(t1 + 2, 0),
                  asm volatile("s_waitcnt vmcnt(4)" ::: "memory"));
        }
    }

    // Epilogue: C/D layout col = lane&15 (pixel), row = (lane>>4)*4 + e (o)
    float* outb = out + (size_t)b * COUT * HW;
    const int g4 = q * 4;
    #pragma unroll
    for (int am = 0; am < 8; ++am) {
        const int o = wm * 128 + am * 16 + g4;
        #pragma unroll
        for (int e = 0; e < 4; ++e) {
            const float bv = aggb[b * COUT + o + e];
            #pragma unroll
            for (int ni = 0; ni < 4; ++ni) {
                const int p = p0 + wn * 64 + ni * 16 + m;
                if (p < HW) outb[(size_t)(o + e) * HW + p] = acc[am][ni][e] + bv;
            }
        }
    }
}

// ---------------------------------------------------------------------------
// Launch
// ---------------------------------------------------------------------------
extern "C" void kernel_launch(void* const* d_in, const int* in_sizes, int n_in,
                              void* d_out, int out_size, void* d_ws, size_t ws_size,
                              hipStream_t stream) {
    const float* x      = (const float*)d_in[0];
    const float* weight = (const float*)d_in[1];
    const float* bias   = (const float*)d_in[2];
    const float* fc1w   = (const float*)d_in[3];
    const float* fc1b   = (const float*)d_in[4];
    const float* fc2w   = (const float*)d_in[5];
    const float* fc2b   = (const float*)d_in[6];
    float* out = (float*)d_out;

    char* ws = (char*)d_ws;
    // workspace layout (256 B aligned)
    unsigned short* xt      = (unsigned short*)(ws);              // 55,115,776 B
    unsigned short* aggw    = (unsigned short*)(ws + 55115776);   // 37,748,736 B
    float*          partial = (float*)(ws + 92864512);            //  1,835,008 B
    float*          att     = (float*)(ws + 94699520);            //        512 B
    float*          aggb    = (float*)(ws + 94700032);            //     32,768 B

    transpose_pool_kernel<<<BB * HH, 256, 0, stream>>>(x, xt, partial);
    attn_kernel<<<BB, 256, 0, stream>>>(partial, fc1w, fc1b, fc2w, fc2b, att);
    aggw_kernel<<<COUT * 4, 256, 0, stream>>>(weight, bias, att, aggw, aggb);
    conv_gemm_kernel<<<BB * 13, 512, 0, stream>>>(xt, aggw, aggb, out);
}

// Round 3
// 363.976 us; speedup vs baseline: 1.0306x; 1.0057x over previous
//
#include <hip/hip_runtime.h>
#include <hip/hip_bf16.h>
#include <stdint.h>

// Problem constants
#define BB   32
#define CIN  256
#define COUT 256
#define HH   56
#define WW   56
#define HW   3136           // 56*56
#define KEXP 4
#define HP   58             // padded spatial (1-px zero halo)

typedef __attribute__((ext_vector_type(8))) short  short8;
typedef __attribute__((ext_vector_type(4))) float  floatx4;

__device__ __forceinline__ unsigned short f2bf(float f) {
    uint32_t u = __float_as_uint(f);
    u = (u + 0x7fffu + ((u >> 16) & 1u)) >> 16;
    return (unsigned short)u;
}
__device__ __forceinline__ float bf2f(unsigned short s) {
    return __uint_as_float(((uint32_t)s) << 16);
}
__device__ __forceinline__ uint32_t pack2(float a, float b) {
    return (uint32_t)f2bf(a) | ((uint32_t)f2bf(b) << 16);
}

__device__ __forceinline__ void async_copy16(const void* gsrc, void* ldst) {
    __builtin_amdgcn_global_load_lds(
        (const __attribute__((address_space(1))) unsigned int*)gsrc,
        (__attribute__((address_space(3))) unsigned int*)ldst, 16, 0, 0);
}

// ---------------------------------------------------------------------------
// Kernel T: NCHW fp32 -> padded NHWC bf16, plus per-(b,h) pool partials.
// ---------------------------------------------------------------------------
__global__ __launch_bounds__(256) void transpose_pool_kernel(
    const float* __restrict__ x,          // [B][CIN][H][W]
    unsigned short* __restrict__ xt,      // [B][58][58][CIN] bf16, halo zero
    float* __restrict__ partial)          // [B][H][CIN] row sums
{
    __shared__ unsigned short tile[CIN * 62];   // [c][w] stride 62: bank-safe
    const int bx  = blockIdx.x;
    const int b   = bx / HH;
    const int h   = bx % HH;
    const int tid = threadIdx.x;

    const float* xb = x + (size_t)b * CIN * HW + h * WW;

    for (int i = tid; i < CIN * 14; i += 256) {
        const int c  = i / 14;
        const int wv = i % 14;
        const float4 v = *(const float4*)(xb + (size_t)c * HW + wv * 4);
        uint32_t* p = (uint32_t*)&tile[c * 62 + wv * 4];
        p[0] = pack2(v.x, v.y);
        p[1] = pack2(v.z, v.w);
    }
    __syncthreads();

    // per-channel row sum (c = tid)
    {
        float s = 0.f;
        #pragma unroll 8
        for (int i = 0; i < WW; ++i) s += bf2f(tile[tid * 62 + i]);
        partial[((size_t)b * HH + h) * CIN + tid] = s;
    }

    // padded NHWC write, 2 channels per lane (4 B stores)
    unsigned short* row = xt + (((size_t)b * HP + (h + 1)) * HP) * CIN;
    for (int j = tid; j < WW * 128; j += 256) {
        const int w  = j >> 7;
        const int c2 = (j & 127) * 2;
        const uint32_t v = (uint32_t)tile[c2 * 62 + w]
                         | ((uint32_t)tile[(c2 + 1) * 62 + w] << 16);
        *(uint32_t*)&row[(w + 1) * CIN + c2] = v;
    }

    // halo: w'=0 and w'=57 of this row
    if (tid < 128) {
        ((uint32_t*)&row[0])[tid]          = 0u;
        ((uint32_t*)&row[57 * CIN])[tid]   = 0u;
    }
    // halo: full rows h'=0 and h'=57 (only h==0 blocks)
    if (h == 0) {
        uint32_t* r0  = (uint32_t*)(xt + ((size_t)b * HP + 0)  * HP * CIN);
        uint32_t* r57 = (uint32_t*)(xt + ((size_t)b * HP + 57) * HP * CIN);
        for (int i = tid; i < HP * 128; i += 256) { r0[i] = 0u; r57[i] = 0u; }
    }
}

// ---------------------------------------------------------------------------
// Kernel A: pool-partial reduce + attention MLP + softmax -> att[B][K]
// ---------------------------------------------------------------------------
__global__ __launch_bounds__(256) void attn_kernel(
    const float* __restrict__ partial,  // [B][H][CIN]
    const float* __restrict__ fc1w,     // [K][CIN]
    const float* __restrict__ fc1b,     // [K]
    const float* __restrict__ fc2w,     // [K][K]
    const float* __restrict__ fc2b,     // [K]
    float* __restrict__ att)            // [B][K]
{
    __shared__ float pl[CIN];
    const int b   = blockIdx.x;
    const int tid = threadIdx.x;

    float s = 0.f;
    const float* pp = partial + (size_t)b * HH * CIN + tid;
    #pragma unroll 8
    for (int h = 0; h < HH; ++h) s += pp[h * CIN];
    pl[tid] = s * (1.0f / (float)HW);
    __syncthreads();

    if (tid < 64) {
        const int lane = tid;
        float sk[KEXP] = {0.f, 0.f, 0.f, 0.f};
        #pragma unroll
        for (int c0 = 0; c0 < CIN; c0 += 64) {
            const float p = pl[c0 + lane];
            #pragma unroll
            for (int k = 0; k < KEXP; ++k) sk[k] += p * fc1w[k * CIN + c0 + lane];
        }
        #pragma unroll
        for (int off = 32; off > 0; off >>= 1) {
            #pragma unroll
            for (int k = 0; k < KEXP; ++k) sk[k] += __shfl_down(sk[k], off);
        }
        if (lane == 0) {
            float a[KEXP];
            #pragma unroll
            for (int k = 0; k < KEXP; ++k) a[k] = fmaxf(sk[k] + fc1b[k], 0.f);
            float z[KEXP], m = -1e30f;
            #pragma unroll
            for (int j = 0; j < KEXP; ++j) {
                float t = fc2b[j];
                #pragma unroll
                for (int k = 0; k < KEXP; ++k) t += a[k] * fc2w[j * KEXP + k];
                z[j] = t;
                m = fmaxf(m, t);
            }
            float den = 0.f;
            #pragma unroll
            for (int j = 0; j < KEXP; ++j) { z[j] = expf(z[j] - m); den += z[j]; }
            const float inv = 1.0f / den;
            #pragma unroll
            for (int j = 0; j < KEXP; ++j) att[b * KEXP + j] = z[j] * inv;
        }
    }
}

// ---------------------------------------------------------------------------
// Kernel W: aggregate expert weights -> agg_w[b][rs][o][c] (bf16), agg_b[b][o]
// ---------------------------------------------------------------------------
__global__ __launch_bounds__(256) void aggw_kernel(
    const float* __restrict__ weight,   // [K][COUT][CIN][3][3]
    const float* __restrict__ bias,     // [K][COUT]
    const float* __restrict__ att,      // [B][K]
    unsigned short* __restrict__ aggw,  // [B][9][COUT][CIN] bf16
    float* __restrict__ aggb)           // [B][COUT]
{
    __shared__ float accw[CIN * 9];     // staging for (c,rs)->(rs,c) transpose
    const int bx  = blockIdx.x;
    const int o   = bx >> 2;
    const int b0  = (bx & 3) * 8;
    const int tid = threadIdx.x;

    float wreg[KEXP][9];
    #pragma unroll
    for (int k = 0; k < KEXP; ++k) {
        const float* wk = weight + (size_t)(k * COUT + o) * (CIN * 9);
        #pragma unroll
        for (int j = 0; j < 9; ++j) wreg[k][j] = wk[j * 256 + tid];
    }
    float bvals[KEXP];
    #pragma unroll
    for (int k = 0; k < KEXP; ++k) bvals[k] = bias[k * COUT + o];

    for (int bi = 0; bi < 8; ++bi) {
        const int b = b0 + bi;
        float av[KEXP];
        #pragma unroll
        for (int k = 0; k < KEXP; ++k) av[k] = att[b * KEXP + k];

        __syncthreads();   // previous iteration's accw reads complete
        #pragma unroll
        for (int j = 0; j < 9; ++j) {
            float r = 0.f;
            #pragma unroll
            for (int k = 0; k < KEXP; ++k) r += av[k] * wreg[k][j];
            accw[j * 256 + tid] = r;   // accw[flat] mirrors weight-flat layout
        }
        __syncthreads();

        // element (c, rs) = accw[c*9 + rs]; write [rs][c] packed pairs
        for (int i = tid; i < 9 * 128; i += 256) {
            const int j  = i >> 7;          // rs
            const int cp = (i & 127) * 2;   // channel pair
            const uint32_t v = pack2(accw[cp * 9 + j], accw[(cp + 1) * 9 + j]);
            *(uint32_t*)&aggw[(((size_t)b * 9 + j) * COUT + o) * CIN + cp] = v;
        }
        if (tid == 0) {
            float sb = 0.f;
            #pragma unroll
            for (int k = 0; k < KEXP; ++k) sb += av[k] * bvals[k];
            aggb[b * COUT + o] = sb;
        }
    }
}

// ---------------------------------------------------------------------------
// Kernel G: per-sample implicit-im2col GEMM, 256x256 tile, 8-phase pipelined.
//
// ROUND 2 FIX (resubmitted after infra timeout): the Round-1 port wrapped
// barriers in `asm("" ::: "memory")` fences. A "memory" clobber may read the
// LDS destinations of in-flight global_load_lds ops, so the compiler must
// drain vmcnt to 0 before it — per phase — which silently reduced the
// schedule to the m97 drain-per-step structure (measured: MfmaUtil 31%,
// unchanged vs baseline). This version uses only sched_barrier(0) for
// compile-time ordering (no memory semantics), raw s_barrier, explicit
// clobber-free counted s_waitcnt:
//   ds_reads | stage -> SB0 -> bar -> "lgkmcnt(0)" -> SB0 -> prio1 16xMFMA
//   prio0 -> [ph4: "vmcnt(4)"] -> SB0 -> bar -> SB0
// Pipeline invariant (per-wave loads, 2 per half): at each tile entry,
// outstanding = next tile's ks0 halves (4 loads) only; every ds_read is
// covered by a vmcnt(4)+barrier pair upstream (verified per phase).
// ---------------------------------------------------------------------------
#define PHASE(MH, KS, LOADB, STAGE_STMT, VM_STMT) do {                         \
    const char* Ap_ = lds + bufoff + (KS) * 16384 + lnoff;                     \
    const char* Bp_ = lds + bufoff + 32768 + (KS) * 16384 + lnoff;             \
    short8 af_[4];                                                             \
    if (LOADB) {                                                               \
        _Pragma("unroll")                                                      \
        for (int ni_ = 0; ni_ < 4; ++ni_)                                      \
            bf[ni_] = *(const short8*)(Bp_ + wn * 4096 + ni_ * 1024);          \
    }                                                                          \
    _Pragma("unroll")                                                          \
    for (int mi_ = 0; mi_ < 4; ++mi_)                                          \
        af_[mi_] = *(const short8*)(Ap_ + wm * 8192 + (MH) * 4096 + mi_ * 1024); \
    STAGE_STMT;                                                                \
    __builtin_amdgcn_sched_barrier(0);                                         \
    __builtin_amdgcn_s_barrier();                                              \
    asm volatile("s_waitcnt lgkmcnt(0)");                                      \
    __builtin_amdgcn_sched_barrier(0);                                         \
    __builtin_amdgcn_s_setprio(1);                                             \
    _Pragma("unroll")                                                          \
    for (int mi_ = 0; mi_ < 4; ++mi_)                                          \
        _Pragma("unroll")                                                      \
        for (int ni_ = 0; ni_ < 4; ++ni_)                                      \
            acc[(MH) * 4 + mi_][ni_] = __builtin_amdgcn_mfma_f32_16x16x32_bf16( \
                af_[mi_], bf[ni_], acc[(MH) * 4 + mi_][ni_], 0, 0, 0);         \
    __builtin_amdgcn_s_setprio(0);                                             \
    __builtin_amdgcn_sched_barrier(0);                                         \
    VM_STMT;                                                                   \
    __builtin_amdgcn_sched_barrier(0);                                         \
    __builtin_amdgcn_s_barrier();                                              \
    __builtin_amdgcn_sched_barrier(0);                                         \
} while (0)

__global__ __launch_bounds__(512, 2) void conv_gemm_kernel(
    const unsigned short* __restrict__ xt,    // [B][58][58][CIN] bf16 padded
    const unsigned short* __restrict__ aggw,  // [B][9][COUT][CIN] bf16
    const float* __restrict__ aggb,           // [B][COUT]
    float* __restrict__ out)                  // [B][COUT][HW]
{
    __shared__ __attribute__((aligned(128))) char lds[131072];

    // grid 416 = 32 b x 13 n-tiles; bijective XCD chunking (416 % 8 == 0).
    const int bx = blockIdx.x;
    const int wg = (bx & 7) * 52 + (bx >> 3);
    const int b  = wg / 13;
    const int p0 = (wg - b * 13) * 256;

    const int tid  = threadIdx.x;
    const int wave = tid >> 6;
    const int lane = tid & 63;
    const int wm   = wave >> 2;                 // 0..1 (M half)
    const int wn   = wave & 3;                  // 0..3 (N quarter)
    const int m    = lane & 15;
    const int q    = lane >> 4;                 // 0..3 k-chunk of fragment
    const int lnoff = m * 64 + ((q ^ (m >> 1)) & 3) * 16;  // read swizzle

    const char* aggw_b = (const char*)aggw + (size_t)b * (9 * COUT * CIN * 2);
    const char* xt_b   = (const char*)xt   + (size_t)b * (HP * HP * CIN * 2);

    // staging geometry: unit n = j*512 + tid; row r = n>>2; chunk u = n&3
    int aoff0, aoff1, boff0, boff1;
    {
        int n = tid, r = n >> 2, u = n & 3, sw = (u ^ (r >> 1)) & 3;
        aoff0 = r * 512 + sw * 16;
        int p = p0 + r; int pv = (p < HW) ? p : 0;
        int h = pv / WW, w = pv - h * WW;
        boff0 = ((h + 1) * HP + (w + 1)) * 512 + sw * 16;

        n = 512 + tid; r = n >> 2; u = n & 3; sw = (u ^ (r >> 1)) & 3;
        aoff1 = r * 512 + sw * 16;
        p = p0 + r; pv = (p < HW) ? p : 0;
        h = pv / WW; w = pv - h * WW;
        boff1 = ((h + 1) * HP + (w + 1)) * 512 + sw * 16;
    }

    auto stageA = [&](int kt, int ks) {
        const int ga = (kt >> 2) * (COUT * CIN * 2) + (kt & 3) * 128 + ks * 64;
        char* d = lds + (kt & 1) * 65536 + ks * 16384 + wave * 1024;
        async_copy16(aggw_b + (size_t)(ga + aoff0), d);
        async_copy16(aggw_b + (size_t)(ga + aoff1), d + 8192);
    };
    auto stageB = [&](int kt, int ks) {
        const int rs = kt >> 2;
        const int gb = ((rs / 3 - 1) * HP + (rs % 3 - 1)) * 512
                     + (kt & 3) * 128 + ks * 64;
        char* d = lds + (kt & 1) * 65536 + 32768 + ks * 16384 + wave * 1024;
        async_copy16(xt_b + (size_t)(gb + boff0), d);
        async_copy16(xt_b + (size_t)(gb + boff1), d + 8192);
    };

    floatx4 acc[8][4];
    #pragma unroll
    for (int a_ = 0; a_ < 8; ++a_)
        #pragma unroll
        for (int n_ = 0; n_ < 4; ++n_)
            #pragma unroll
            for (int e_ = 0; e_ < 4; ++e_) acc[a_][n_][e_] = 0.f;

    // Prologue: tile 0 complete + tile 1 ks0 in flight.
    stageA(0, 0); stageB(0, 0);
    stageA(0, 1); stageB(0, 1);
    stageA(1, 0); stageB(1, 0);
    __builtin_amdgcn_sched_barrier(0);
    asm volatile("s_waitcnt vmcnt(4)");
    __builtin_amdgcn_sched_barrier(0);
    __builtin_amdgcn_s_barrier();
    __builtin_amdgcn_sched_barrier(0);

    // 36 K-tiles (9 taps x 4 channel-blocks), 2 tiles per iteration.
    #pragma unroll 1
    for (int i = 0; i < 18; ++i) {
        const int t0 = 2 * i;
        {
            const int bufoff = 0;
            short8 bf[4];
            PHASE(0, 0, 1, stageA(t0 + 1, 1), ((void)0));
            PHASE(1, 0, 0, stageB(t0 + 1, 1), ((void)0));
            PHASE(1, 1, 1, if (i < 17) stageA(t0 + 2, 0), ((void)0));
            PHASE(0, 1, 0, if (i < 17) stageB(t0 + 2, 0),
                  if (i < 17) { asm volatile("s_waitcnt vmcnt(4)"); }
                  else        { asm volatile("s_waitcnt vmcnt(0)"); });
        }
        {
            const int bufoff = 65536;
            const int t1 = 2 * i + 1;
            short8 bf[4];
            PHASE(0, 0, 1, if (i < 17) stageA(t1 + 1, 1), ((void)0));
            PHASE(1, 0, 0, if (i < 17) stageB(t1 + 1, 1), ((void)0));
            PHASE(1, 1, 1, if (i < 17) stageA(t1 + 2, 0), ((void)0));
            PHASE(0, 1, 0, if (i < 17) stageB(t1 + 2, 0),
                  asm volatile("s_waitcnt vmcnt(4)"));
        }
    }

    // Epilogue: C/D layout col = lane&15 (pixel), row = (lane>>4)*4 + e (o)
    float* outb = out + (size_t)b * COUT * HW;
    const int g4 = q * 4;
    #pragma unroll
    for (int am = 0; am < 8; ++am) {
        const int o = wm * 128 + am * 16 + g4;
        #pragma unroll
        for (int e = 0; e < 4; ++e) {
            const float bv = aggb[b * COUT + o + e];
            #pragma unroll
            for (int ni = 0; ni < 4; ++ni) {
                const int p = p0 + wn * 64 + ni * 16 + m;
                if (p < HW) outb[(size_t)(o + e) * HW + p] = acc[am][ni][e] + bv;
            }
        }
    }
}

// ---------------------------------------------------------------------------
// Launch
// ---------------------------------------------------------------------------
extern "C" void kernel_launch(void* const* d_in, const int* in_sizes, int n_in,
                              void* d_out, int out_size, void* d_ws, size_t ws_size,
                              hipStream_t stream) {
    const float* x      = (const float*)d_in[0];
    const float* weight = (const float*)d_in[1];
    const float* bias   = (const float*)d_in[2];
    const float* fc1w   = (const float*)d_in[3];
    const float* fc1b   = (const float*)d_in[4];
    const float* fc2w   = (const float*)d_in[5];
    const float* fc2b   = (const float*)d_in[6];
    float* out = (float*)d_out;

    char* ws = (char*)d_ws;
    // workspace layout (256 B aligned)
    unsigned short* xt      = (unsigned short*)(ws);              // 55,115,776 B
    unsigned short* aggw    = (unsigned short*)(ws + 55115776);   // 37,748,736 B
    float*          partial = (float*)(ws + 92864512);            //  1,835,008 B
    float*          att     = (float*)(ws + 94699520);            //        512 B
    float*          aggb    = (float*)(ws + 94700032);            //     32,768 B

    transpose_pool_kernel<<<BB * HH, 256, 0, stream>>>(x, xt, partial);
    attn_kernel<<<BB, 256, 0, stream>>>(partial, fc1w, fc1b, fc2w, fc2b, att);
    aggw_kernel<<<COUT * 4, 256, 0, stream>>>(weight, bias, att, aggw, aggb);
    conv_gemm_kernel<<<BB * 13, 512, 0, stream>>>(xt, aggw, aggb, out);
}

// Round 4
// 353.709 us; speedup vs baseline: 1.0606x; 1.0290x over previous
//
#include <hip/hip_runtime.h>
#include <hip/hip_bf16.h>
#include <stdint.h>

// Problem constants
#define BB   32
#define CIN  256
#define COUT 256
#define HH   56
#define WW   56
#define HW   3136           // 56*56
#define KEXP 4
#define HP   58             // padded spatial (1-px zero halo)

typedef __attribute__((ext_vector_type(8))) short  short8;
typedef __attribute__((ext_vector_type(4))) float  floatx4;

__device__ __forceinline__ unsigned short f2bf(float f) {
    uint32_t u = __float_as_uint(f);
    u = (u + 0x7fffu + ((u >> 16) & 1u)) >> 16;
    return (unsigned short)u;
}
__device__ __forceinline__ float bf2f(unsigned short s) {
    return __uint_as_float(((uint32_t)s) << 16);
}
__device__ __forceinline__ uint32_t pack2(float a, float b) {
    return (uint32_t)f2bf(a) | ((uint32_t)f2bf(b) << 16);
}

__device__ __forceinline__ void async_copy16(const void* gsrc, void* ldst) {
    __builtin_amdgcn_global_load_lds(
        (const __attribute__((address_space(1))) unsigned int*)gsrc,
        (__attribute__((address_space(3))) unsigned int*)ldst, 16, 0, 0);
}

// ---------------------------------------------------------------------------
// Kernel T: NCHW fp32 -> padded NHWC bf16, plus per-(b,h) pool partials.
// ---------------------------------------------------------------------------
__global__ __launch_bounds__(256) void transpose_pool_kernel(
    const float* __restrict__ x,          // [B][CIN][H][W]
    unsigned short* __restrict__ xt,      // [B][58][58][CIN] bf16, halo zero
    float* __restrict__ partial)          // [B][H][CIN] row sums
{
    __shared__ unsigned short tile[CIN * 62];   // [c][w] stride 62: bank-safe
    const int bx  = blockIdx.x;
    const int b   = bx / HH;
    const int h   = bx % HH;
    const int tid = threadIdx.x;

    const float* xb = x + (size_t)b * CIN * HW + h * WW;

    for (int i = tid; i < CIN * 14; i += 256) {
        const int c  = i / 14;
        const int wv = i % 14;
        const float4 v = *(const float4*)(xb + (size_t)c * HW + wv * 4);
        uint32_t* p = (uint32_t*)&tile[c * 62 + wv * 4];
        p[0] = pack2(v.x, v.y);
        p[1] = pack2(v.z, v.w);
    }
    __syncthreads();

    // per-channel row sum (c = tid)
    {
        float s = 0.f;
        #pragma unroll 8
        for (int i = 0; i < WW; ++i) s += bf2f(tile[tid * 62 + i]);
        partial[((size_t)b * HH + h) * CIN + tid] = s;
    }

    // padded NHWC write, 2 channels per lane (4 B stores)
    unsigned short* row = xt + (((size_t)b * HP + (h + 1)) * HP) * CIN;
    for (int j = tid; j < WW * 128; j += 256) {
        const int w  = j >> 7;
        const int c2 = (j & 127) * 2;
        const uint32_t v = (uint32_t)tile[c2 * 62 + w]
                         | ((uint32_t)tile[(c2 + 1) * 62 + w] << 16);
        *(uint32_t*)&row[(w + 1) * CIN + c2] = v;
    }

    // halo: w'=0 and w'=57 of this row
    if (tid < 128) {
        ((uint32_t*)&row[0])[tid]          = 0u;
        ((uint32_t*)&row[57 * CIN])[tid]   = 0u;
    }
    // halo: full rows h'=0 and h'=57 (only h==0 blocks)
    if (h == 0) {
        uint32_t* r0  = (uint32_t*)(xt + ((size_t)b * HP + 0)  * HP * CIN);
        uint32_t* r57 = (uint32_t*)(xt + ((size_t)b * HP + 57) * HP * CIN);
        for (int i = tid; i < HP * 128; i += 256) { r0[i] = 0u; r57[i] = 0u; }
    }
}

// ---------------------------------------------------------------------------
// Kernel A: pool-partial reduce + attention MLP + softmax -> att[B][K]
// ---------------------------------------------------------------------------
__global__ __launch_bounds__(256) void attn_kernel(
    const float* __restrict__ partial,  // [B][H][CIN]
    const float* __restrict__ fc1w,     // [K][CIN]
    const float* __restrict__ fc1b,     // [K]
    const float* __restrict__ fc2w,     // [K][K]
    const float* __restrict__ fc2b,     // [K]
    float* __restrict__ att)            // [B][K]
{
    __shared__ float pl[CIN];
    const int b   = blockIdx.x;
    const int tid = threadIdx.x;

    float s = 0.f;
    const float* pp = partial + (size_t)b * HH * CIN + tid;
    #pragma unroll 8
    for (int h = 0; h < HH; ++h) s += pp[h * CIN];
    pl[tid] = s * (1.0f / (float)HW);
    __syncthreads();

    if (tid < 64) {
        const int lane = tid;
        float sk[KEXP] = {0.f, 0.f, 0.f, 0.f};
        #pragma unroll
        for (int c0 = 0; c0 < CIN; c0 += 64) {
            const float p = pl[c0 + lane];
            #pragma unroll
            for (int k = 0; k < KEXP; ++k) sk[k] += p * fc1w[k * CIN + c0 + lane];
        }
        #pragma unroll
        for (int off = 32; off > 0; off >>= 1) {
            #pragma unroll
            for (int k = 0; k < KEXP; ++k) sk[k] += __shfl_down(sk[k], off);
        }
        if (lane == 0) {
            float a[KEXP];
            #pragma unroll
            for (int k = 0; k < KEXP; ++k) a[k] = fmaxf(sk[k] + fc1b[k], 0.f);
            float z[KEXP], m = -1e30f;
            #pragma unroll
            for (int j = 0; j < KEXP; ++j) {
                float t = fc2b[j];
                #pragma unroll
                for (int k = 0; k < KEXP; ++k) t += a[k] * fc2w[j * KEXP + k];
                z[j] = t;
                m = fmaxf(m, t);
            }
            float den = 0.f;
            #pragma unroll
            for (int j = 0; j < KEXP; ++j) { z[j] = expf(z[j] - m); den += z[j]; }
            const float inv = 1.0f / den;
            #pragma unroll
            for (int j = 0; j < KEXP; ++j) att[b * KEXP + j] = z[j] * inv;
        }
    }
}

// ---------------------------------------------------------------------------
// Kernel W: aggregate expert weights -> agg_w[b][rs][o][c] (bf16), agg_b[b][o]
// ---------------------------------------------------------------------------
__global__ __launch_bounds__(256) void aggw_kernel(
    const float* __restrict__ weight,   // [K][COUT][CIN][3][3]
    const float* __restrict__ bias,     // [K][COUT]
    const float* __restrict__ att,      // [B][K]
    unsigned short* __restrict__ aggw,  // [B][9][COUT][CIN] bf16
    float* __restrict__ aggb)           // [B][COUT]
{
    __shared__ float accw[CIN * 9];     // staging for (c,rs)->(rs,c) transpose
    const int bx  = blockIdx.x;
    const int o   = bx >> 2;
    const int b0  = (bx & 3) * 8;
    const int tid = threadIdx.x;

    float wreg[KEXP][9];
    #pragma unroll
    for (int k = 0; k < KEXP; ++k) {
        const float* wk = weight + (size_t)(k * COUT + o) * (CIN * 9);
        #pragma unroll
        for (int j = 0; j < 9; ++j) wreg[k][j] = wk[j * 256 + tid];
    }
    float bvals[KEXP];
    #pragma unroll
    for (int k = 0; k < KEXP; ++k) bvals[k] = bias[k * COUT + o];

    for (int bi = 0; bi < 8; ++bi) {
        const int b = b0 + bi;
        float av[KEXP];
        #pragma unroll
        for (int k = 0; k < KEXP; ++k) av[k] = att[b * KEXP + k];

        __syncthreads();   // previous iteration's accw reads complete
        #pragma unroll
        for (int j = 0; j < 9; ++j) {
            float r = 0.f;
            #pragma unroll
            for (int k = 0; k < KEXP; ++k) r += av[k] * wreg[k][j];
            accw[j * 256 + tid] = r;   // accw[flat] mirrors weight-flat layout
        }
        __syncthreads();

        // element (c, rs) = accw[c*9 + rs]; write [rs][c] packed pairs
        for (int i = tid; i < 9 * 128; i += 256) {
            const int j  = i >> 7;          // rs
            const int cp = (i & 127) * 2;   // channel pair
            const uint32_t v = pack2(accw[cp * 9 + j], accw[(cp + 1) * 9 + j]);
            *(uint32_t*)&aggw[(((size_t)b * 9 + j) * COUT + o) * CIN + cp] = v;
        }
        if (tid == 0) {
            float sb = 0.f;
            #pragma unroll
            for (int k = 0; k < KEXP; ++k) sb += av[k] * bvals[k];
            aggb[b * COUT + o] = sb;
        }
    }
}

// ---------------------------------------------------------------------------
// Kernel G: per-sample implicit-im2col GEMM, 256x256 tile.
//
// ROUND 4: software-pipelined tile schedule, 2 barriers/tile (was 8).
// R1/R3 post-mortem: the per-phase [reads -> bar -> MFMA -> bar] skeleton
// exposed LDS latency serially every phase (reads issued between two
// barriers with nothing to hide under), and SB0/memory fences forbade the
// compiler from fixing it. MfmaUtil stuck at 29-31%.
//
// New per-tile schedule (parity par = t&1 selects 64KB buffer):
//   [entry bar]
//   G1 reads: A(ks0,MH0) x4, B(ks0) x4, A(ks0,MH1) x4   (12 ds_read_b128)
//   stage A(t+1,ks1); stage B(t+1,ks1)       // opposite buffer, idle since
//                                            // end-bar of tile t-1
//   MFMA ph1 (acc 0..3 += a0*b0)             // compiler auto-lgkmcnt
//   G2a reads: A(ks1,MH1) x4, B(ks1) x4      // service under ph2 MFMA
//   MFMA ph2 (acc 4..7 += a1*b0)
//   [mid bar]   // all waves' ks0 reads consumed => ks0 regions overwritable
//   stage A(t+2,ks0); stage B(t+2,ks0)       // same buffer, ks0 regions
//   G2b reads: A(ks1,MH0) x4
//   MFMA ph3 (acc 4..7 += a2*b1)
//   MFMA ph4 (acc 0..3 += a3*b1)
//   s_waitcnt vmcnt(4)                       // tile t+1 fully landed;
//                                            // t+2 ks0 (4 loads) in flight
//   [end bar]
// sched_barrier(0) ONLY around the two s_barriers (cross-wave safety:
// no LDS-read hoist above entry bar, no MFMA sink below mid/end bar).
// Reads/stages are otherwise free to float under MFMA.
// vmcnt FIFO invariant (2 loads per stage call, per wave): entering tile t
// only t+1's ks0 (4) is outstanding; during t issue 8 more; vmcnt(4) at
// end leaves t+2's ks0. Prologue establishes it; tiles 34/35 peeled
// (34: only t+1ks1 stages + vmcnt(0); 35: no stages).
// ---------------------------------------------------------------------------
#define MM(AB, AF, BF) do {                                                    \
    __builtin_amdgcn_s_setprio(1);                                             \
    _Pragma("unroll")                                                          \
    for (int mi_ = 0; mi_ < 4; ++mi_)                                          \
        _Pragma("unroll")                                                      \
        for (int ni_ = 0; ni_ < 4; ++ni_)                                      \
            acc[(AB) + mi_][ni_] = __builtin_amdgcn_mfma_f32_16x16x32_bf16(    \
                AF[mi_], BF[ni_], acc[(AB) + mi_][ni_], 0, 0, 0);              \
    __builtin_amdgcn_s_setprio(0);                                             \
} while (0)

#define TILE(BUF, S1A, S1B, S2A, S2B, VMSTMT) do {                             \
    const char* A0_ = lds + (BUF) + lnoff;                                     \
    const char* B0_ = lds + (BUF) + 32768 + lnoff;                             \
    short8 a0[4], a1[4], a2[4], a3[4], b0[4], b1[4];                           \
    _Pragma("unroll")                                                          \
    for (int i_ = 0; i_ < 4; ++i_)                                             \
        a0[i_] = *(const short8*)(A0_ + wm * 8192 + i_ * 1024);                \
    _Pragma("unroll")                                                          \
    for (int i_ = 0; i_ < 4; ++i_)                                             \
        b0[i_] = *(const short8*)(B0_ + wn * 4096 + i_ * 1024);                \
    _Pragma("unroll")                                                          \
    for (int i_ = 0; i_ < 4; ++i_)                                             \
        a1[i_] = *(const short8*)(A0_ + wm * 8192 + 4096 + i_ * 1024);         \
    S1A; S1B;                                                                  \
    MM(0, a0, b0);                                                             \
    _Pragma("unroll")                                                          \
    for (int i_ = 0; i_ < 4; ++i_)                                             \
        a2[i_] = *(const short8*)(A0_ + 16384 + wm * 8192 + 4096 + i_ * 1024); \
    _Pragma("unroll")                                                          \
    for (int i_ = 0; i_ < 4; ++i_)                                             \
        b1[i_] = *(const short8*)(B0_ + 16384 + wn * 4096 + i_ * 1024);        \
    MM(4, a1, b0);                                                             \
    __builtin_amdgcn_sched_barrier(0);                                         \
    __builtin_amdgcn_s_barrier();                                              \
    __builtin_amdgcn_sched_barrier(0);                                         \
    S2A; S2B;                                                                  \
    _Pragma("unroll")                                                          \
    for (int i_ = 0; i_ < 4; ++i_)                                             \
        a3[i_] = *(const short8*)(A0_ + 16384 + wm * 8192 + i_ * 1024);        \
    MM(4, a2, b1);                                                             \
    MM(0, a3, b1);                                                             \
    __builtin_amdgcn_sched_barrier(0);                                         \
    VMSTMT;                                                                    \
    __builtin_amdgcn_s_barrier();                                              \
    __builtin_amdgcn_sched_barrier(0);                                         \
} while (0)

__global__ __launch_bounds__(512, 2) void conv_gemm_kernel(
    const unsigned short* __restrict__ xt,    // [B][58][58][CIN] bf16 padded
    const unsigned short* __restrict__ aggw,  // [B][9][COUT][CIN] bf16
    const float* __restrict__ aggb,           // [B][COUT]
    float* __restrict__ out)                  // [B][COUT][HW]
{
    __shared__ __attribute__((aligned(128))) char lds[131072];

    // grid 416 = 32 b x 13 n-tiles; bijective XCD chunking (416 % 8 == 0).
    const int bx = blockIdx.x;
    const int wg = (bx & 7) * 52 + (bx >> 3);
    const int b  = wg / 13;
    const int p0 = (wg - b * 13) * 256;

    const int tid  = threadIdx.x;
    const int wave = tid >> 6;
    const int lane = tid & 63;
    const int wm   = wave >> 2;                 // 0..1 (M half)
    const int wn   = wave & 3;                  // 0..3 (N quarter)
    const int m    = lane & 15;
    const int q    = lane >> 4;                 // 0..3 k-chunk of fragment
    const int lnoff = m * 64 + ((q ^ (m >> 1)) & 3) * 16;  // read swizzle

    const char* aggw_b = (const char*)aggw + (size_t)b * (9 * COUT * CIN * 2);
    const char* xt_b   = (const char*)xt   + (size_t)b * (HP * HP * CIN * 2);

    // staging geometry: unit n = j*512 + tid; row r = n>>2; chunk u = n&3
    int aoff0, aoff1, boff0, boff1;
    {
        int n = tid, r = n >> 2, u = n & 3, sw = (u ^ (r >> 1)) & 3;
        aoff0 = r * 512 + sw * 16;
        int p = p0 + r; int pv = (p < HW) ? p : 0;
        int h = pv / WW, w = pv - h * WW;
        boff0 = ((h + 1) * HP + (w + 1)) * 512 + sw * 16;

        n = 512 + tid; r = n >> 2; u = n & 3; sw = (u ^ (r >> 1)) & 3;
        aoff1 = r * 512 + sw * 16;
        p = p0 + r; pv = (p < HW) ? p : 0;
        h = pv / WW; w = pv - h * WW;
        boff1 = ((h + 1) * HP + (w + 1)) * 512 + sw * 16;
    }

    auto stageA = [&](int kt, int ks) {
        const int ga = (kt >> 2) * (COUT * CIN * 2) + (kt & 3) * 128 + ks * 64;
        char* d = lds + (kt & 1) * 65536 + ks * 16384 + wave * 1024;
        async_copy16(aggw_b + (size_t)(ga + aoff0), d);
        async_copy16(aggw_b + (size_t)(ga + aoff1), d + 8192);
    };
    auto stageB = [&](int kt, int ks) {
        const int rs = kt >> 2;
        const int gb = ((rs / 3 - 1) * HP + (rs % 3 - 1)) * 512
                     + (kt & 3) * 128 + ks * 64;
        char* d = lds + (kt & 1) * 65536 + 32768 + ks * 16384 + wave * 1024;
        async_copy16(xt_b + (size_t)(gb + boff0), d);
        async_copy16(xt_b + (size_t)(gb + boff1), d + 8192);
    };

    floatx4 acc[8][4];
    #pragma unroll
    for (int a_ = 0; a_ < 8; ++a_)
        #pragma unroll
        for (int n_ = 0; n_ < 4; ++n_)
            #pragma unroll
            for (int e_ = 0; e_ < 4; ++e_) acc[a_][n_][e_] = 0.f;

    // Prologue: tile 0 complete + tile 1 ks0 in flight (vmcnt FIFO:
    // [t0ks0:4][t0ks1:4][t1ks0:4] -> vmcnt(4) lands t0 fully).
    stageA(0, 0); stageB(0, 0);
    stageA(0, 1); stageB(0, 1);
    stageA(1, 0); stageB(1, 0);
    __builtin_amdgcn_sched_barrier(0);
    asm volatile("s_waitcnt vmcnt(4)");
    __builtin_amdgcn_sched_barrier(0);
    __builtin_amdgcn_s_barrier();
    __builtin_amdgcn_sched_barrier(0);

    // 36 K-tiles (9 taps x 4 channel-blocks); tiles 34,35 peeled.
    #pragma unroll 1
    for (int i = 0; i < 17; ++i) {
        const int t0 = 2 * i;
        const int t1 = 2 * i + 1;
        TILE(0,
             stageA(t0 + 1, 1), stageB(t0 + 1, 1),
             stageA(t0 + 2, 0), stageB(t0 + 2, 0),
             asm volatile("s_waitcnt vmcnt(4)"));
        TILE(65536,
             stageA(t1 + 1, 1), stageB(t1 + 1, 1),
             stageA(t1 + 2, 0), stageB(t1 + 2, 0),
             asm volatile("s_waitcnt vmcnt(4)"));
    }
    // tile 34 (buf0): stage only t+1 ks1; drain so tile 35 is fully landed.
    TILE(0,
         stageA(35, 1), stageB(35, 1),
         ((void)0), ((void)0),
         asm volatile("s_waitcnt vmcnt(0)"));
    // tile 35 (buf1): nothing left to stage or wait on.
    TILE(65536, ((void)0), ((void)0), ((void)0), ((void)0), ((void)0));

    // Epilogue: C/D layout col = lane&15 (pixel), row = (lane>>4)*4 + e (o)
    float* outb = out + (size_t)b * COUT * HW;
    const int g4 = q * 4;
    #pragma unroll
    for (int am = 0; am < 8; ++am) {
        const int o = wm * 128 + am * 16 + g4;
        #pragma unroll
        for (int e = 0; e < 4; ++e) {
            const float bv = aggb[b * COUT + o + e];
            #pragma unroll
            for (int ni = 0; ni < 4; ++ni) {
                const int p = p0 + wn * 64 + ni * 16 + m;
                if (p < HW) outb[(size_t)(o + e) * HW + p] = acc[am][ni][e] + bv;
            }
        }
    }
}

// ---------------------------------------------------------------------------
// Launch
// ---------------------------------------------------------------------------
extern "C" void kernel_launch(void* const* d_in, const int* in_sizes, int n_in,
                              void* d_out, int out_size, void* d_ws, size_t ws_size,
                              hipStream_t stream) {
    const float* x      = (const float*)d_in[0];
    const float* weight = (const float*)d_in[1];
    const float* bias   = (const float*)d_in[2];
    const float* fc1w   = (const float*)d_in[3];
    const float* fc1b   = (const float*)d_in[4];
    const float* fc2w   = (const float*)d_in[5];
    const float* fc2b   = (const float*)d_in[6];
    float* out = (float*)d_out;

    char* ws = (char*)d_ws;
    // workspace layout (256 B aligned)
    unsigned short* xt      = (unsigned short*)(ws);              // 55,115,776 B
    unsigned short* aggw    = (unsigned short*)(ws + 55115776);   // 37,748,736 B
    float*          partial = (float*)(ws + 92864512);            //  1,835,008 B
    float*          att     = (float*)(ws + 94699520);            //        512 B
    float*          aggb    = (float*)(ws + 94700032);            //     32,768 B

    transpose_pool_kernel<<<BB * HH, 256, 0, stream>>>(x, xt, partial);
    attn_kernel<<<BB, 256, 0, stream>>>(partial, fc1w, fc1b, fc2w, fc2b, att);
    aggw_kernel<<<COUT * 4, 256, 0, stream>>>(weight, bias, att, aggw, aggb);
    conv_gemm_kernel<<<BB * 13, 512, 0, stream>>>(xt, aggw, aggb, out);
}